// Round 2
// baseline (643.140 us; speedup 1.0000x reference)
//
#include <hip/hip_runtime.h>
#include <hip/hip_cooperative_groups.h>

namespace cg = cooperative_groups;

#define DIM  64
#define TPB  256

// =====================================================================
// Fused cooperative kernel: zero -> hist -> scan -> scatter -> AP -> reduce
// Grid size is RUNTIME-determined (occupancy query), passed via gridDim.x.
// =====================================================================
__global__ __launch_bounds__(TPB, 4) void fused_ap(
    const float* __restrict__ d1, const float* __restrict__ d2,
    const float* __restrict__ qw, const float* __restrict__ qb,
    const int* __restrict__ m1, const int* __restrict__ m2,
    const int* __restrict__ offs,
    int* __restrict__ cnt, int* __restrict__ i1s, int* __restrict__ i2s,
    float* __restrict__ blocksum, float* __restrict__ out,
    int P, int NEG, int NQ2, int N)
{
    cg::grid_group grid = cg::this_grid();

    __shared__ int   s_scan[256];
    __shared__ float s_scores[2][2][96];   // [it&1][match A/B][score j]
    __shared__ float s_red[4];

    const int tid   = threadIdx.x;
    const int b     = blockIdx.x;
    const int nG    = gridDim.x;           // multiple of 8 (host guarantees)
    const int gtid  = b * TPB + tid;
    const int gstr  = nG * TPB;
    const int nbuck = (P + 127) >> 7;

    // ---- phase 0: zero histogram ----
    for (int i = gtid; i < nbuck; i += gstr) cnt[i] = 0;
    __threadfence();
    grid.sync();

    // ---- phase 1: histogram (bucket = 128 rows of d2) ----
    for (int i = gtid; i < N; i += gstr) atomicAdd(&cnt[m2[i] >> 7], 1);
    __threadfence();
    grid.sync();

    // ---- phase 2: exclusive scan over buckets (block 0 only) ----
    if (b == 0) {
        const int base = tid * 10;
        int loc[10];
        int sum = 0;
        #pragma unroll
        for (int u = 0; u < 10; ++u) {
            const int idx = base + u;
            const int v = (idx < nbuck) ? cnt[idx] : 0;
            loc[u] = sum;
            sum += v;
        }
        s_scan[tid] = sum;
        __syncthreads();
        for (int off = 1; off < 256; off <<= 1) {
            const int v = (tid >= off) ? s_scan[tid - off] : 0;
            __syncthreads();
            s_scan[tid] += v;
            __syncthreads();
        }
        const int excl = (tid > 0) ? s_scan[tid - 1] : 0;
        #pragma unroll
        for (int u = 0; u < 10; ++u) {
            const int idx = base + u;
            if (idx < nbuck) cnt[idx] = excl + loc[u];
        }
    }
    __threadfence();
    grid.sync();

    // ---- phase 3: scatter (counting sort by m2 bucket) ----
    for (int i = gtid; i < N; i += gstr) {
        const int v2  = m2[i];
        const int pos = atomicAdd(&cnt[v2 >> 7], 1);
        i1s[pos] = m1[i];
        i2s[pos] = v2;
    }
    __threadfence();
    grid.sync();

    // ---- phase 4: AP main over pairs of sorted matches.
    //      XCD-contiguous mapping: blocks with b%8==x walk consecutive
    //      pairs of slice x concurrently (L2 locality). ----
    const int npair = (N + 1) >> 1;
    const int per8  = (npair + 7) >> 3;
    const int pbeg  = (b & 7) * per8;
    const int pend  = (pbeg + per8 < npair) ? (pbeg + per8) : npair;
    const int slots = nG >> 3;
    const int g     = tid >> 3;          // group 0..31
    const int sl    = tid & 7;           // 8 lanes x 32B = 256B per row
    const int w     = tid >> 6;          // wave id
    const int lane  = tid & 63;
    const int M     = NEG + 1;           // 81 scores per match
    const int nq    = NQ2 >> 1;
    const float a_scale = qw[nq];               // +a
    const float amn     = qb[nq - 1] - 1.0f;    // a*mn
    const float ulim    = (float)(nq - 1);

    float acc = 0.0f;                    // live at tid 0 (A) and tid 64 (B)
    int it = 0;
    for (int pr = pbeg + (b >> 3); pr < pend; pr += slots, ++it) {
        float (*sc)[96] = s_scores[it & 1];
        const int posA = 2 * pr;
        const int posB = posA + 1;
        const bool hasB = (posB < N);
        const int i1A = i1s[posA];
        const int i2A = i2s[posA];
        const int i1B = hasB ? i1s[posB] : i1A;
        const int i2B = hasB ? i2s[posB] : i2A;

        const float* aA = d1 + (size_t)i1A * DIM + 8 * sl;
        const float* aB = d1 + (size_t)i1B * DIM + 8 * sl;
        const float4 a0A = ((const float4*)aA)[0];
        const float4 a1A = ((const float4*)aA)[1];
        const float4 a0B = ((const float4*)aB)[0];
        const float4 a1B = ((const float4*)aB)[1];

        int rA[3], rB[3];
        #pragma unroll
        for (int t = 0; t < 3; ++t) {
            const int j = g + 32 * t;
            if (j < M) {
                const int o = (j == 0) ? 0 : offs[j - 1];
                rA[t] = (j == 0) ? i2A : min(i2A + o, P - 1);
                rB[t] = (j == 0) ? i2B : min(i2B + o, P - 1);
            }
        }

        // all 12 b-loads in flight before any math
        float4 b0A[3], b1A[3], b0B[3], b1B[3];
        #pragma unroll
        for (int t = 0; t < 3; ++t) {
            const int j = g + 32 * t;
            if (j < M) {
                const float* pA = d2 + (size_t)rA[t] * DIM + 8 * sl;
                b0A[t] = ((const float4*)pA)[0];
                b1A[t] = ((const float4*)pA)[1];
                const float* pB = d2 + (size_t)rB[t] * DIM + 8 * sl;
                b0B[t] = ((const float4*)pB)[0];
                b1B[t] = ((const float4*)pB)[1];
            }
        }
        #pragma unroll
        for (int t = 0; t < 3; ++t) {
            const int j = g + 32 * t;
            if (j < M) {
                float sA = b0A[t].x * a0A.x + b0A[t].y * a0A.y + b0A[t].z * a0A.z + b0A[t].w * a0A.w
                         + b1A[t].x * a1A.x + b1A[t].y * a1A.y + b1A[t].z * a1A.z + b1A[t].w * a1A.w;
                float sB = b0B[t].x * a0B.x + b0B[t].y * a0B.y + b0B[t].z * a0B.z + b0B[t].w * a0B.w
                         + b1B[t].x * a1B.x + b1B[t].y * a1B.y + b1B[t].z * a1B.z + b1B[t].w * a1B.w;
                sA += __shfl_xor(sA, 1);
                sA += __shfl_xor(sA, 2);
                sA += __shfl_xor(sA, 4);
                sB += __shfl_xor(sB, 1);
                sB += __shfl_xor(sB, 2);
                sB += __shfl_xor(sB, 4);
                if (sl == 0) {
                    sc[0][j] = sA;
                    sc[1][j] = sB;
                }
            }
        }
        __syncthreads();
        // epilogue (waves 0/1) overlaps next iter's fill; 2-iter buffer reuse
        if (w < 2 && (w == 0 || hasB)) {
            const float xp = sc[w][0];
            const float up = fminf(fmaxf(a_scale * xp - amn, 0.0f), ulim);
            const float ip = floorf(up);
            const float fp = up - ip;

            float n1 = 0.0f, n2 = 0.0f;
            {
                const float x  = sc[w][lane];
                const float u  = fminf(fmaxf(a_scale * x - amn, 0.0f), ulim);
                const float fi = floorf(u);
                const float f  = u - fi;
                n2 += (fi >= ip)        ? 1.0f : ((fi == ip - 1.0f) ? f : 0.0f);
                n1 += (fi >= ip + 1.0f) ? 1.0f : ((fi == ip)        ? f : 0.0f);
            }
            if (lane + 64 < M) {
                const float x  = sc[w][lane + 64];
                const float u  = fminf(fmaxf(a_scale * x - amn, 0.0f), ulim);
                const float fi = floorf(u);
                const float f  = u - fi;
                n2 += (fi >= ip)        ? 1.0f : ((fi == ip - 1.0f) ? f : 0.0f);
                n1 += (fi >= ip + 1.0f) ? 1.0f : ((fi == ip)        ? f : 0.0f);
            }
            #pragma unroll
            for (int off = 32; off >= 1; off >>= 1) {
                n1 += __shfl_xor(n1, off);
                n2 += __shfl_xor(n2, off);
            }
            if (lane == 0) {
                const float ap = fp * fp / (1e-16f + n1) + (1.0f - fp) / (1e-16f + n2);
                acc += 1.0f - ap;
            }
        }
    }

    __syncthreads();
    if (tid == 0)  s_red[0] = acc;
    if (tid == 64) s_red[1] = acc;
    __syncthreads();
    if (tid == 0) blocksum[b] = s_red[0] + s_red[1];
    __threadfence();
    grid.sync();

    // ---- phase 5: final deterministic reduction (block 0) ----
    if (b == 0) {
        float s = 0.0f;
        for (int i = tid; i < nG; i += TPB) s += blocksum[i];
        #pragma unroll
        for (int off = 32; off >= 1; off >>= 1) s += __shfl_xor(s, off);
        __syncthreads();
        if ((tid & 63) == 0) s_red[tid >> 6] = s;
        __syncthreads();
        if (tid == 0) out[0] = (s_red[0] + s_red[1] + s_red[2] + s_red[3]) / (float)N;
    }
}

// =====================================================================
// Fallback: proven 6-dispatch pipeline (R0, 198 us, passed)
// =====================================================================
__global__ __launch_bounds__(256) void k_hist(const int* __restrict__ m2,
                                              int* __restrict__ cnt, int N) {
    const int i = blockIdx.x * 256 + threadIdx.x;
    if (i < N) atomicAdd(&cnt[m2[i] >> 7], 1);
}

__global__ __launch_bounds__(256) void k_scan(int* __restrict__ cnt, int nbuck) {
    __shared__ int s[256];
    const int tid  = threadIdx.x;
    const int base = tid * 10;
    int loc[10];
    int sum = 0;
    #pragma unroll
    for (int u = 0; u < 10; ++u) {
        const int idx = base + u;
        const int v = (idx < nbuck) ? cnt[idx] : 0;
        loc[u] = sum;
        sum += v;
    }
    s[tid] = sum;
    __syncthreads();
    for (int off = 1; off < 256; off <<= 1) {
        const int v = (tid >= off) ? s[tid - off] : 0;
        __syncthreads();
        s[tid] += v;
        __syncthreads();
    }
    const int excl = (tid > 0) ? s[tid - 1] : 0;
    #pragma unroll
    for (int u = 0; u < 10; ++u) {
        const int idx = base + u;
        if (idx < nbuck) cnt[idx] = excl + loc[u];
    }
}

__global__ __launch_bounds__(256) void k_scatter(const int* __restrict__ m1,
                                                 const int* __restrict__ m2,
                                                 int* __restrict__ cnt,
                                                 int* __restrict__ i1s,
                                                 int* __restrict__ i2s, int N) {
    const int i = blockIdx.x * 256 + threadIdx.x;
    if (i < N) {
        const int v2  = m2[i];
        const int pos = atomicAdd(&cnt[v2 >> 7], 1);
        i1s[pos] = m1[i];
        i2s[pos] = v2;
    }
}

__global__ __launch_bounds__(256) void pixel_ap_main(
    const float* __restrict__ d1, const float* __restrict__ d2,
    const float* __restrict__ qw, const float* __restrict__ qb,
    const int* __restrict__ offs,
    const int* __restrict__ i1s, const int* __restrict__ i2s,
    float* __restrict__ partial, int P, int NEG, int NQ2, int N)
{
    const int tid = threadIdx.x;
    const int nq  = NQ2 >> 1;
    const int M   = NEG + 1;

    __shared__ float s_scores[2][96];

    const int b    = blockIdx.x;
    const int per  = gridDim.x >> 3;
    const int pr   = (b & 7) * per + (b >> 3);
    const int posA = 2 * pr;
    const int posB = posA + 1;
    if (posA >= N) return;
    const bool hasB = (posB < N);

    const int i1A = i1s[posA];
    const int i2A = i2s[posA];
    const int i1B = hasB ? i1s[posB] : i1A;
    const int i2B = hasB ? i2s[posB] : i2A;

    const int g  = tid >> 3;
    const int sl = tid & 7;

    const float* aA = d1 + (size_t)i1A * DIM + 8 * sl;
    const float* aB = d1 + (size_t)i1B * DIM + 8 * sl;
    const float4 a0A = ((const float4*)aA)[0];
    const float4 a1A = ((const float4*)aA)[1];
    const float4 a0B = ((const float4*)aB)[0];
    const float4 a1B = ((const float4*)aB)[1];

    int rA[3], rB[3];
    #pragma unroll
    for (int t = 0; t < 3; ++t) {
        const int j = g + 32 * t;
        if (j < M) {
            const int o = (j == 0) ? 0 : offs[j - 1];
            rA[t] = (j == 0) ? i2A : min(i2A + o, P - 1);
            rB[t] = (j == 0) ? i2B : min(i2B + o, P - 1);
        }
    }

    float4 b0A[3], b1A[3], b0B[3], b1B[3];
    #pragma unroll
    for (int t = 0; t < 3; ++t) {
        const int j = g + 32 * t;
        if (j < M) {
            const float* pA = d2 + (size_t)rA[t] * DIM + 8 * sl;
            b0A[t] = ((const float4*)pA)[0];
            b1A[t] = ((const float4*)pA)[1];
            const float* pB = d2 + (size_t)rB[t] * DIM + 8 * sl;
            b0B[t] = ((const float4*)pB)[0];
            b1B[t] = ((const float4*)pB)[1];
        }
    }
    #pragma unroll
    for (int t = 0; t < 3; ++t) {
        const int j = g + 32 * t;
        if (j < M) {
            float sA = b0A[t].x * a0A.x + b0A[t].y * a0A.y + b0A[t].z * a0A.z + b0A[t].w * a0A.w
                     + b1A[t].x * a1A.x + b1A[t].y * a1A.y + b1A[t].z * a1A.z + b1A[t].w * a1A.w;
            float sB = b0B[t].x * a0B.x + b0B[t].y * a0B.y + b0B[t].z * a0B.z + b0B[t].w * a0B.w
                     + b1B[t].x * a1B.x + b1B[t].y * a1B.y + b1B[t].z * a1B.z + b1B[t].w * a1B.w;
            sA += __shfl_xor(sA, 1);
            sA += __shfl_xor(sA, 2);
            sA += __shfl_xor(sA, 4);
            sB += __shfl_xor(sB, 1);
            sB += __shfl_xor(sB, 2);
            sB += __shfl_xor(sB, 4);
            if (sl == 0) {
                s_scores[0][j] = sA;
                s_scores[1][j] = sB;
            }
        }
    }
    __syncthreads();
    const int w = tid >> 6;
    if (w >= 2) return;
    if (w == 1 && !hasB) return;
    const int lane = tid & 63;

    const float a_scale = qw[nq];
    const float amn     = qb[nq - 1] - 1.0f;
    const float ulim    = (float)(nq - 1);

    const float xp = s_scores[w][0];
    const float up = fminf(fmaxf(a_scale * xp - amn, 0.0f), ulim);
    const float ip = floorf(up);
    const float fp = up - ip;

    float n1 = 0.0f, n2 = 0.0f;
    {
        const float x  = s_scores[w][lane];
        const float u  = fminf(fmaxf(a_scale * x - amn, 0.0f), ulim);
        const float fi = floorf(u);
        const float f  = u - fi;
        n2 += (fi >= ip)        ? 1.0f : ((fi == ip - 1.0f) ? f : 0.0f);
        n1 += (fi >= ip + 1.0f) ? 1.0f : ((fi == ip)        ? f : 0.0f);
    }
    if (lane + 64 < M) {
        const float x  = s_scores[w][lane + 64];
        const float u  = fminf(fmaxf(a_scale * x - amn, 0.0f), ulim);
        const float fi = floorf(u);
        const float f  = u - fi;
        n2 += (fi >= ip)        ? 1.0f : ((fi == ip - 1.0f) ? f : 0.0f);
        n1 += (fi >= ip + 1.0f) ? 1.0f : ((fi == ip)        ? f : 0.0f);
    }
    #pragma unroll
    for (int off = 32; off >= 1; off >>= 1) {
        n1 += __shfl_xor(n1, off);
        n2 += __shfl_xor(n2, off);
    }
    if (lane == 0) {
        const float ap = fp * fp / (1e-16f + n1) + (1.0f - fp) / (1e-16f + n2);
        partial[posA + w] = 1.0f - ap;
    }
}

__global__ __launch_bounds__(1024) void k_reduce(const float* __restrict__ partial,
                                                 float* __restrict__ out, int N)
{
    float s = 0.0f;
    for (int i = threadIdx.x; i < N; i += 1024) s += partial[i];
    #pragma unroll
    for (int off = 32; off >= 1; off >>= 1) s += __shfl_xor(s, off);
    __shared__ float sw[16];
    if ((threadIdx.x & 63) == 0) sw[threadIdx.x >> 6] = s;
    __syncthreads();
    if (threadIdx.x == 0) {
        float t = 0.0f;
        #pragma unroll
        for (int w = 0; w < 16; ++w) t += sw[w];
        out[0] = t / (float)N;
    }
}

// =====================================================================
extern "C" void kernel_launch(void* const* d_in, const int* in_sizes, int n_in,
                              void* d_out, int out_size, void* d_ws, size_t ws_size,
                              hipStream_t stream) {
    const float* d1   = (const float*)d_in[0];
    const float* d2   = (const float*)d_in[1];
    const float* qw   = (const float*)d_in[2];
    const float* qb   = (const float*)d_in[3];
    const int*   m1   = (const int*)d_in[4];
    const int*   m2   = (const int*)d_in[5];
    const int*   offs = (const int*)d_in[6];

    int N   = in_sizes[4];
    int P   = in_sizes[0] / DIM;
    int NEG = in_sizes[6];
    int NQ2 = in_sizes[2];
    const int nbuck = (P + 127) >> 7;

    int*   cnt      = (int*)d_ws;
    int*   i1s      = cnt + nbuck;
    int*   i2s      = i1s + N;
    float* blocksum = (float*)(i2s + N);   // also 'partial' in fallback path
    float* outp     = (float*)d_out;

    // One-time: size the cooperative grid from the runtime's own occupancy
    // computation (the same check hipLaunchCooperativeKernel enforces).
    static int s_grid = -2;                // -2 = not yet queried
    if (s_grid == -2) {
        int blocksPerCU = 0;
        hipError_t e1 = hipOccupancyMaxActiveBlocksPerMultiprocessor(
            &blocksPerCU, fused_ap, TPB, 0);
        int numCU = 0;
        hipError_t e2 = hipDeviceGetAttribute(
            &numCU, hipDeviceAttributeMultiprocessorCount, 0);
        if (e1 == hipSuccess && e2 == hipSuccess && blocksPerCU > 0 && numCU > 0) {
            int maxg = blocksPerCU * numCU;
            if (maxg > 2048) maxg = 2048;
            s_grid = (maxg / 8) * 8;       // multiple of 8 for XCD mapping
            if (s_grid < 8) s_grid = -1;   // cooperative not viable
        } else {
            s_grid = -1;
        }
    }

    hipError_t err = hipErrorUnknown;
    if (s_grid >= 8) {
        void* args[] = { (void*)&d1, (void*)&d2, (void*)&qw, (void*)&qb,
                         (void*)&m1, (void*)&m2, (void*)&offs,
                         (void*)&cnt, (void*)&i1s, (void*)&i2s,
                         (void*)&blocksum, (void*)&outp,
                         (void*)&P, (void*)&NEG, (void*)&NQ2, (void*)&N };
        err = hipLaunchCooperativeKernel(fused_ap, dim3(s_grid), dim3(TPB),
                                         args, 0, stream);
    }

    if (err != hipSuccess) {
        // Proven 6-dispatch fallback (R0 path).
        s_grid = -1;                       // don't retry cooperative next call
        const int nblk = (N + 255) / 256;
        hipMemsetAsync(cnt, 0, (size_t)nbuck * sizeof(int), stream);
        k_hist   <<<nblk, 256, 0, stream>>>(m2, cnt, N);
        k_scan   <<<1, 256, 0, stream>>>(cnt, nbuck);
        k_scatter<<<nblk, 256, 0, stream>>>(m1, m2, cnt, i1s, i2s, N);
        const int npair = (N + 1) / 2;
        const int per   = (npair + 7) / 8;
        pixel_ap_main<<<8 * per, 256, 0, stream>>>(d1, d2, qw, qb, offs,
                                                   i1s, i2s, blocksum,
                                                   P, NEG, NQ2, N);
        k_reduce<<<1, 1024, 0, stream>>>(blocksum, outp, N);
    }
}

// Round 4
// 626.730 us; speedup vs baseline: 1.0262x; 1.0262x over previous
//
#include <hip/hip_runtime.h>

#define DIM 64

// =====================================================================
// Kernel 1: single-block LDS counting sort (hist+scan+scatter fused)
//           + zeroes the accumulator/done counter for kernel 2.
// Replaces memset + k_hist + k_scan + k_scatter (4 dispatches -> 1).
// =====================================================================
__global__ __launch_bounds__(1024) void k_sort(
    const int* __restrict__ m1, const int* __restrict__ m2,
    int* __restrict__ i1s, int* __restrict__ i2s,
    float* __restrict__ acc, unsigned int* __restrict__ done,
    int N, int nbuck, int shift)
{
    __shared__ int h[3072];      // bucket histogram / running offsets
    __shared__ int ssc[1024];    // block-scan workspace
    const int tid = threadIdx.x;

    if (tid == 0) { acc[0] = 0.0f; done[0] = 0u; }
    for (int i = tid; i < nbuck; i += 1024) h[i] = 0;
    __syncthreads();

    // histogram (LDS atomics)
    for (int i = tid; i < N; i += 1024) atomicAdd(&h[m2[i] >> shift], 1);
    __syncthreads();

    // exclusive scan over h[0..nbuck): 3 buckets/thread + Hillis-Steele
    const int base = tid * 3;
    int l0 = 0, l1 = 0, l2 = 0, sum = 0;
    if (base + 0 < nbuck) { l0 = sum; sum += h[base + 0]; }
    if (base + 1 < nbuck) { l1 = sum; sum += h[base + 1]; }
    if (base + 2 < nbuck) { l2 = sum; sum += h[base + 2]; }
    ssc[tid] = sum;
    __syncthreads();
    for (int off = 1; off < 1024; off <<= 1) {
        const int v = (tid >= off) ? ssc[tid - off] : 0;
        __syncthreads();
        ssc[tid] += v;
        __syncthreads();
    }
    const int excl = (tid > 0) ? ssc[tid - 1] : 0;
    if (base + 0 < nbuck) h[base + 0] = excl + l0;
    if (base + 1 < nbuck) h[base + 1] = excl + l1;
    if (base + 2 < nbuck) h[base + 2] = excl + l2;
    __syncthreads();

    // scatter (counting sort by m2 bucket)
    for (int i = tid; i < N; i += 1024) {
        const int v2  = m2[i];
        const int pos = atomicAdd(&h[v2 >> shift], 1);
        i1s[pos] = m1[i];
        i2s[pos] = v2;
    }
}

// =====================================================================
// Kernel 2: AP main (proven R6/R0 body, return-free) + fused final
//           reduction via last-block-done pattern (replaces k_reduce).
// =====================================================================
__global__ __launch_bounds__(256) void pixel_ap_main(
    const float* __restrict__ d1, const float* __restrict__ d2,
    const float* __restrict__ qw, const float* __restrict__ qb,
    const int* __restrict__ offs,
    const int* __restrict__ i1s, const int* __restrict__ i2s,
    float* __restrict__ acc, unsigned int* __restrict__ done,
    float* __restrict__ out, int P, int NEG, int NQ2, int N)
{
    const int tid = threadIdx.x;
    const int nq  = NQ2 >> 1;
    const int M   = NEG + 1;          // 81 scores per match

    __shared__ float s_scores[2][96];

    // XCD-aware contiguous slice over pair-index space (block b -> XCD b%8)
    const int b    = blockIdx.x;
    const int per  = gridDim.x >> 3;                // gridDim = 8*per
    const int pr   = (b & 7) * per + (b >> 3);      // pair index
    const int posA = 2 * pr;
    const int posB = posA + 1;
    const bool active = (posA < N);
    const bool hasB   = (posB < N);

    const int g  = tid >> 3;          // group 0..31
    const int sl = tid & 7;           // 8 lanes x 32 B = 256 B per row
    const int w  = tid >> 6;          // wave id
    const int lane = tid & 63;

    if (active) {
        const int i1A = i1s[posA];
        const int i2A = i2s[posA];
        const int i1B = hasB ? i1s[posB] : i1A;
        const int i2B = hasB ? i2s[posB] : i2A;

        const float* aA = d1 + (size_t)i1A * DIM + 8 * sl;
        const float* aB = d1 + (size_t)i1B * DIM + 8 * sl;
        const float4 a0A = ((const float4*)aA)[0];
        const float4 a1A = ((const float4*)aA)[1];
        const float4 a0B = ((const float4*)aB)[0];
        const float4 a1B = ((const float4*)aB)[1];

        int rA[3], rB[3];
        #pragma unroll
        for (int t = 0; t < 3; ++t) {
            const int j = g + 32 * t;
            if (j < M) {
                const int o = (j == 0) ? 0 : offs[j - 1];
                rA[t] = (j == 0) ? i2A : min(i2A + o, P - 1);
                rB[t] = (j == 0) ? i2B : min(i2B + o, P - 1);
            }
        }

        // all 12 b-loads in flight before any math
        float4 b0A[3], b1A[3], b0B[3], b1B[3];
        #pragma unroll
        for (int t = 0; t < 3; ++t) {
            const int j = g + 32 * t;
            if (j < M) {
                const float* pA = d2 + (size_t)rA[t] * DIM + 8 * sl;
                b0A[t] = ((const float4*)pA)[0];
                b1A[t] = ((const float4*)pA)[1];
                const float* pB = d2 + (size_t)rB[t] * DIM + 8 * sl;
                b0B[t] = ((const float4*)pB)[0];
                b1B[t] = ((const float4*)pB)[1];
            }
        }
        #pragma unroll
        for (int t = 0; t < 3; ++t) {
            const int j = g + 32 * t;
            if (j < M) {
                float sA = b0A[t].x * a0A.x + b0A[t].y * a0A.y + b0A[t].z * a0A.z + b0A[t].w * a0A.w
                         + b1A[t].x * a1A.x + b1A[t].y * a1A.y + b1A[t].z * a1A.z + b1A[t].w * a1A.w;
                float sB = b0B[t].x * a0B.x + b0B[t].y * a0B.y + b0B[t].z * a0B.z + b0B[t].w * a0B.w
                         + b1B[t].x * a1B.x + b1B[t].y * a1B.y + b1B[t].z * a1B.z + b1B[t].w * a1B.w;
                sA += __shfl_xor(sA, 1);
                sA += __shfl_xor(sA, 2);
                sA += __shfl_xor(sA, 4);
                sB += __shfl_xor(sB, 1);
                sB += __shfl_xor(sB, 2);
                sB += __shfl_xor(sB, 4);
                if (sl == 0) {
                    s_scores[0][j] = sA;
                    s_scores[1][j] = sB;
                }
            }
        }
    }
    __syncthreads();

    // ---- hat-basis AP epilogue, one wave per match (predicated) ----
    if (active && w < 2 && (w == 0 || hasB)) {
        const float a_scale = qw[nq];               // +a
        const float amn     = qb[nq - 1] - 1.0f;    // a*mn
        const float ulim    = (float)(nq - 1);

        const float xp = s_scores[w][0];
        const float up = fminf(fmaxf(a_scale * xp - amn, 0.0f), ulim);
        const float ip = floorf(up);
        const float fp = up - ip;

        float n1 = 0.0f, n2 = 0.0f;
        {
            const float x  = s_scores[w][lane];
            const float u  = fminf(fmaxf(a_scale * x - amn, 0.0f), ulim);
            const float fi = floorf(u);
            const float f  = u - fi;
            n2 += (fi >= ip)        ? 1.0f : ((fi == ip - 1.0f) ? f : 0.0f);
            n1 += (fi >= ip + 1.0f) ? 1.0f : ((fi == ip)        ? f : 0.0f);
        }
        if (lane + 64 < M) {
            const float x  = s_scores[w][lane + 64];
            const float u  = fminf(fmaxf(a_scale * x - amn, 0.0f), ulim);
            const float fi = floorf(u);
            const float f  = u - fi;
            n2 += (fi >= ip)        ? 1.0f : ((fi == ip - 1.0f) ? f : 0.0f);
            n1 += (fi >= ip + 1.0f) ? 1.0f : ((fi == ip)        ? f : 0.0f);
        }
        #pragma unroll
        for (int off = 32; off >= 1; off >>= 1) {
            n1 += __shfl_xor(n1, off);
            n2 += __shfl_xor(n2, off);
        }
        if (lane == 0) {
            const float ap = fp * fp / (1e-16f + n1) + (1.0f - fp) / (1e-16f + n2);
            atomicAdd(acc, 1.0f - ap);
        }
    }

    // ---- last-block-done final reduction (replaces k_reduce) ----
    __syncthreads();                  // both waves' acc-atomics issued & drained
    if (tid == 0) {
        __threadfence();              // our adds visible before done-increment
        const unsigned prev = atomicAdd(done, 1u);
        if (prev == (unsigned)(gridDim.x - 1)) {
            const float s = atomicAdd(acc, 0.0f);   // device-scope read
            out[0] = s / (float)N;
        }
    }
}

// =====================================================================
extern "C" void kernel_launch(void* const* d_in, const int* in_sizes, int n_in,
                              void* d_out, int out_size, void* d_ws, size_t ws_size,
                              hipStream_t stream) {
    const float* d1   = (const float*)d_in[0];
    const float* d2   = (const float*)d_in[1];
    const float* qw   = (const float*)d_in[2];
    const float* qb   = (const float*)d_in[3];
    const int*   m1   = (const int*)d_in[4];
    const int*   m2   = (const int*)d_in[5];
    const int*   offs = (const int*)d_in[6];

    const int N   = in_sizes[4];
    const int P   = in_sizes[0] / DIM;
    const int NEG = in_sizes[6];
    const int NQ2 = in_sizes[2];

    // bucket shift: 128-row buckets, widened if P ever exceeds 3072 buckets
    int shift = 7;
    while ((((P - 1) >> shift) + 1) > 3072) ++shift;
    const int nbuck = ((P - 1) >> shift) + 1;

    int*      i1s  = (int*)d_ws;
    int*      i2s  = i1s + N;
    float*    acc  = (float*)(i2s + N);
    unsigned* done = (unsigned*)(acc + 1);

    k_sort<<<1, 1024, 0, stream>>>(m1, m2, i1s, i2s, acc, done, N, nbuck, shift);

    const int npair = (N + 1) / 2;
    const int per   = (npair + 7) / 8;
    pixel_ap_main<<<8 * per, 256, 0, stream>>>(d1, d2, qw, qb, offs, i1s, i2s,
                                               acc, done, (float*)d_out,
                                               P, NEG, NQ2, N);
}

// Round 5
// 243.340 us; speedup vs baseline: 2.6430x; 2.5755x over previous
//
#include <hip/hip_runtime.h>

#define DIM 64

// =====================================================================
// Kernel 1: single-block LDS counting sort (hist+scan+scatter fused).
// Proven in R4. Replaces memset + k_hist + k_scan + k_scatter.
// =====================================================================
__global__ __launch_bounds__(1024) void k_sort(
    const int* __restrict__ m1, const int* __restrict__ m2,
    int* __restrict__ i1s, int* __restrict__ i2s,
    int N, int nbuck, int shift)
{
    __shared__ int h[3072];      // bucket histogram / running offsets
    __shared__ int ssc[1024];    // block-scan workspace
    const int tid = threadIdx.x;

    for (int i = tid; i < nbuck; i += 1024) h[i] = 0;
    __syncthreads();

    // histogram (LDS atomics)
    for (int i = tid; i < N; i += 1024) atomicAdd(&h[m2[i] >> shift], 1);
    __syncthreads();

    // exclusive scan over h[0..nbuck): 3 buckets/thread + Hillis-Steele
    const int base = tid * 3;
    int l0 = 0, l1 = 0, l2 = 0, sum = 0;
    if (base + 0 < nbuck) { l0 = sum; sum += h[base + 0]; }
    if (base + 1 < nbuck) { l1 = sum; sum += h[base + 1]; }
    if (base + 2 < nbuck) { l2 = sum; sum += h[base + 2]; }
    ssc[tid] = sum;
    __syncthreads();
    for (int off = 1; off < 1024; off <<= 1) {
        const int v = (tid >= off) ? ssc[tid - off] : 0;
        __syncthreads();
        ssc[tid] += v;
        __syncthreads();
    }
    const int excl = (tid > 0) ? ssc[tid - 1] : 0;
    if (base + 0 < nbuck) h[base + 0] = excl + l0;
    if (base + 1 < nbuck) h[base + 1] = excl + l1;
    if (base + 2 < nbuck) h[base + 2] = excl + l2;
    __syncthreads();

    // scatter (counting sort by m2 bucket)
    for (int i = tid; i < N; i += 1024) {
        const int v2  = m2[i];
        const int pos = atomicAdd(&h[v2 >> shift], 1);
        i1s[pos] = m1[i];
        i2s[pos] = v2;
    }
}

// =====================================================================
// Kernel 2: AP main — R0-proven body (48 us). One block per TWO sorted
// matches; contention-free partial[] stores (NO global atomics — R4
// showed single-address atomics cost ~400 us under 10k-block contention).
// =====================================================================
__global__ __launch_bounds__(256) void pixel_ap_main(
    const float* __restrict__ d1, const float* __restrict__ d2,
    const float* __restrict__ qw, const float* __restrict__ qb,
    const int* __restrict__ offs,
    const int* __restrict__ i1s, const int* __restrict__ i2s,
    float* __restrict__ partial, int P, int NEG, int NQ2, int N)
{
    const int tid = threadIdx.x;
    const int nq  = NQ2 >> 1;
    const int M   = NEG + 1;          // 81 scores per match

    __shared__ float s_scores[2][96];

    // XCD-aware contiguous slice over pair-index space (block b -> XCD b%8)
    const int b    = blockIdx.x;
    const int per  = gridDim.x >> 3;                // gridDim = 8*per
    const int pr   = (b & 7) * per + (b >> 3);      // pair index
    const int posA = 2 * pr;
    const int posB = posA + 1;
    if (posA >= N) return;
    const bool hasB = (posB < N);

    const int i1A = i1s[posA];
    const int i2A = i2s[posA];
    const int i1B = hasB ? i1s[posB] : i1A;
    const int i2B = hasB ? i2s[posB] : i2A;

    const int g  = tid >> 3;          // group 0..31
    const int sl = tid & 7;           // 8 lanes x 32 B = 256 B per row

    const float* aA = d1 + (size_t)i1A * DIM + 8 * sl;
    const float* aB = d1 + (size_t)i1B * DIM + 8 * sl;
    const float4 a0A = ((const float4*)aA)[0];
    const float4 a1A = ((const float4*)aA)[1];
    const float4 a0B = ((const float4*)aB)[0];
    const float4 a1B = ((const float4*)aB)[1];

    int rA[3], rB[3];
    #pragma unroll
    for (int t = 0; t < 3; ++t) {
        const int j = g + 32 * t;
        if (j < M) {
            const int o = (j == 0) ? 0 : offs[j - 1];
            rA[t] = (j == 0) ? i2A : min(i2A + o, P - 1);
            rB[t] = (j == 0) ? i2B : min(i2B + o, P - 1);
        }
    }

    // all 12 b-loads in flight before any math
    float4 b0A[3], b1A[3], b0B[3], b1B[3];
    #pragma unroll
    for (int t = 0; t < 3; ++t) {
        const int j = g + 32 * t;
        if (j < M) {
            const float* pA = d2 + (size_t)rA[t] * DIM + 8 * sl;
            b0A[t] = ((const float4*)pA)[0];
            b1A[t] = ((const float4*)pA)[1];
            const float* pB = d2 + (size_t)rB[t] * DIM + 8 * sl;
            b0B[t] = ((const float4*)pB)[0];
            b1B[t] = ((const float4*)pB)[1];
        }
    }
    #pragma unroll
    for (int t = 0; t < 3; ++t) {
        const int j = g + 32 * t;
        if (j < M) {
            float sA = b0A[t].x * a0A.x + b0A[t].y * a0A.y + b0A[t].z * a0A.z + b0A[t].w * a0A.w
                     + b1A[t].x * a1A.x + b1A[t].y * a1A.y + b1A[t].z * a1A.z + b1A[t].w * a1A.w;
            float sB = b0B[t].x * a0B.x + b0B[t].y * a0B.y + b0B[t].z * a0B.z + b0B[t].w * a0B.w
                     + b1B[t].x * a1B.x + b1B[t].y * a1B.y + b1B[t].z * a1B.z + b1B[t].w * a1B.w;
            sA += __shfl_xor(sA, 1);
            sA += __shfl_xor(sA, 2);
            sA += __shfl_xor(sA, 4);
            sB += __shfl_xor(sB, 1);
            sB += __shfl_xor(sB, 2);
            sB += __shfl_xor(sB, 4);
            if (sl == 0) {
                s_scores[0][j] = sA;
                s_scores[1][j] = sB;
            }
        }
    }
    __syncthreads();
    const int w = tid >> 6;           // wave id
    if (w >= 2) return;               // waves 2,3 retire
    if (w == 1 && !hasB) return;
    const int lane = tid & 63;

    // ---- hat-basis AP epilogue, one wave per match ----
    const float a_scale = qw[nq];               // +a
    const float amn     = qb[nq - 1] - 1.0f;    // a*mn
    const float ulim    = (float)(nq - 1);

    const float xp = s_scores[w][0];
    const float up = fminf(fmaxf(a_scale * xp - amn, 0.0f), ulim);
    const float ip = floorf(up);
    const float fp = up - ip;

    float n1 = 0.0f, n2 = 0.0f;
    {
        const float x  = s_scores[w][lane];
        const float u  = fminf(fmaxf(a_scale * x - amn, 0.0f), ulim);
        const float fi = floorf(u);
        const float f  = u - fi;
        n2 += (fi >= ip)        ? 1.0f : ((fi == ip - 1.0f) ? f : 0.0f);
        n1 += (fi >= ip + 1.0f) ? 1.0f : ((fi == ip)        ? f : 0.0f);
    }
    if (lane + 64 < M) {
        const float x  = s_scores[w][lane + 64];
        const float u  = fminf(fmaxf(a_scale * x - amn, 0.0f), ulim);
        const float fi = floorf(u);
        const float f  = u - fi;
        n2 += (fi >= ip)        ? 1.0f : ((fi == ip - 1.0f) ? f : 0.0f);
        n1 += (fi >= ip + 1.0f) ? 1.0f : ((fi == ip)        ? f : 0.0f);
    }
    #pragma unroll
    for (int off = 32; off >= 1; off >>= 1) {
        n1 += __shfl_xor(n1, off);
        n2 += __shfl_xor(n2, off);
    }
    if (lane == 0) {
        const float ap = fp * fp / (1e-16f + n1) + (1.0f - fp) / (1e-16f + n2);
        partial[posA + w] = 1.0f - ap;
    }
}

// ---- single-block final reduction (R0-proven) ----
__global__ __launch_bounds__(1024) void k_reduce(const float* __restrict__ partial,
                                                 float* __restrict__ out, int N)
{
    float s = 0.0f;
    for (int i = threadIdx.x; i < N; i += 1024) s += partial[i];
    #pragma unroll
    for (int off = 32; off >= 1; off >>= 1) s += __shfl_xor(s, off);
    __shared__ float sw[16];
    if ((threadIdx.x & 63) == 0) sw[threadIdx.x >> 6] = s;
    __syncthreads();
    if (threadIdx.x == 0) {
        float t = 0.0f;
        #pragma unroll
        for (int w = 0; w < 16; ++w) t += sw[w];
        out[0] = t / (float)N;
    }
}

// =====================================================================
extern "C" void kernel_launch(void* const* d_in, const int* in_sizes, int n_in,
                              void* d_out, int out_size, void* d_ws, size_t ws_size,
                              hipStream_t stream) {
    const float* d1   = (const float*)d_in[0];
    const float* d2   = (const float*)d_in[1];
    const float* qw   = (const float*)d_in[2];
    const float* qb   = (const float*)d_in[3];
    const int*   m1   = (const int*)d_in[4];
    const int*   m2   = (const int*)d_in[5];
    const int*   offs = (const int*)d_in[6];

    const int N   = in_sizes[4];
    const int P   = in_sizes[0] / DIM;
    const int NEG = in_sizes[6];
    const int NQ2 = in_sizes[2];

    // bucket shift: 128-row buckets, widened if P ever exceeds 3072 buckets
    int shift = 7;
    while ((((P - 1) >> shift) + 1) > 3072) ++shift;
    const int nbuck = ((P - 1) >> shift) + 1;

    int*   i1s     = (int*)d_ws;
    int*   i2s     = i1s + N;
    float* partial = (float*)(i2s + N);

    k_sort<<<1, 1024, 0, stream>>>(m1, m2, i1s, i2s, N, nbuck, shift);

    const int npair = (N + 1) / 2;
    const int per   = (npair + 7) / 8;
    pixel_ap_main<<<8 * per, 256, 0, stream>>>(d1, d2, qw, qb, offs, i1s, i2s,
                                               partial, P, NEG, NQ2, N);

    k_reduce<<<1, 1024, 0, stream>>>(partial, (float*)d_out, N);
}

// Round 6
// 205.748 us; speedup vs baseline: 3.1259x; 1.1827x over previous
//
#include <hip/hip_runtime.h>

#define DIM 64

// ---- R0-proven parallel counting-sort pipeline: memset -> hist -> scan -> scatter

__global__ __launch_bounds__(256) void k_hist(const int* __restrict__ m2,
                                              int* __restrict__ cnt, int N) {
    const int i = blockIdx.x * 256 + threadIdx.x;
    if (i < N) atomicAdd(&cnt[m2[i] >> 7], 1);
}

__global__ __launch_bounds__(256) void k_scan(int* __restrict__ cnt, int nbuck) {
    __shared__ int s[256];
    const int tid  = threadIdx.x;
    const int base = tid * 10;
    int loc[10];
    int sum = 0;
    #pragma unroll
    for (int u = 0; u < 10; ++u) {
        const int idx = base + u;
        const int v = (idx < nbuck) ? cnt[idx] : 0;
        loc[u] = sum;
        sum += v;
    }
    s[tid] = sum;
    __syncthreads();
    for (int off = 1; off < 256; off <<= 1) {
        const int v = (tid >= off) ? s[tid - off] : 0;
        __syncthreads();
        s[tid] += v;
        __syncthreads();
    }
    const int excl = (tid > 0) ? s[tid - 1] : 0;
    #pragma unroll
    for (int u = 0; u < 10; ++u) {
        const int idx = base + u;
        if (idx < nbuck) cnt[idx] = excl + loc[u];
    }
}

__global__ __launch_bounds__(256) void k_scatter(const int* __restrict__ m1,
                                                 const int* __restrict__ m2,
                                                 int* __restrict__ cnt,
                                                 int* __restrict__ i1s,
                                                 int* __restrict__ i2s, int N) {
    const int i = blockIdx.x * 256 + threadIdx.x;
    if (i < N) {
        const int v2  = m2[i];
        const int pos = atomicAdd(&cnt[v2 >> 7], 1);
        i1s[pos] = m1[i];
        i2s[pos] = v2;
    }
}

// =====================================================================
// Main V2: one block (256 thr) per FOUR adjacent sorted matches.
// vs R0 (2 matches/block): 24 b-loads in flight per lane (2x MLP),
// one barrier per 4 matches, and ALL FOUR waves run an epilogue
// (R0 idled waves 2,3 there). Cost: VGPR ~36 -> ~160, occupancy drops;
// bet is ILP + epilogue efficiency > occupancy loss.
// =====================================================================
__global__ __launch_bounds__(256) void pixel_ap_main(
    const float* __restrict__ d1, const float* __restrict__ d2,
    const float* __restrict__ qw, const float* __restrict__ qb,
    const int* __restrict__ offs,
    const int* __restrict__ i1s, const int* __restrict__ i2s,
    float* __restrict__ partial, int P, int NEG, int NQ2, int N)
{
    const int tid = threadIdx.x;
    const int nq  = NQ2 >> 1;
    const int M   = NEG + 1;          // 81 scores per match

    __shared__ float s_scores[4][96];

    // XCD-aware contiguous slice over quad-index space (block b -> XCD b%8)
    const int b    = blockIdx.x;
    const int per  = gridDim.x >> 3;                // gridDim = 8*per
    const int qr   = (b & 7) * per + (b >> 3);      // quad index
    const int pos0 = 4 * qr;
    if (pos0 >= N) return;

    const int g  = tid >> 3;          // group 0..31
    const int sl = tid & 7;           // 8 lanes x 32 B = 256 B per row

    // match indices (clamped to last valid for tail quads; stores are guarded)
    int i1[4], i2[4];
    #pragma unroll
    for (int x = 0; x < 4; ++x) {
        const int p = min(pos0 + x, N - 1);
        i1[x] = i1s[p];
        i2[x] = i2s[p];
    }

    // a-fragments for all four matches
    float4 a0[4], a1[4];
    #pragma unroll
    for (int x = 0; x < 4; ++x) {
        const float* a = d1 + (size_t)i1[x] * DIM + 8 * sl;
        a0[x] = ((const float4*)a)[0];
        a1[x] = ((const float4*)a)[1];
    }

    // row indices for 3 scores per match
    int r[4][3];
    #pragma unroll
    for (int t = 0; t < 3; ++t) {
        const int j = g + 32 * t;
        if (j < M) {
            const int o = (j == 0) ? 0 : offs[j - 1];
            #pragma unroll
            for (int x = 0; x < 4; ++x)
                r[x][t] = (j == 0) ? i2[x] : min(i2[x] + o, P - 1);
        }
    }

    // all 24 b-loads issued before any math
    float4 b0[4][3], b1[4][3];
    #pragma unroll
    for (int t = 0; t < 3; ++t) {
        const int j = g + 32 * t;
        if (j < M) {
            #pragma unroll
            for (int x = 0; x < 4; ++x) {
                const float* p = d2 + (size_t)r[x][t] * DIM + 8 * sl;
                b0[x][t] = ((const float4*)p)[0];
                b1[x][t] = ((const float4*)p)[1];
            }
        }
    }

    #pragma unroll
    for (int t = 0; t < 3; ++t) {
        const int j = g + 32 * t;
        if (j < M) {
            #pragma unroll
            for (int x = 0; x < 4; ++x) {
                float s = b0[x][t].x * a0[x].x + b0[x][t].y * a0[x].y
                        + b0[x][t].z * a0[x].z + b0[x][t].w * a0[x].w
                        + b1[x][t].x * a1[x].x + b1[x][t].y * a1[x].y
                        + b1[x][t].z * a1[x].z + b1[x][t].w * a1[x].w;
                s += __shfl_xor(s, 1);
                s += __shfl_xor(s, 2);
                s += __shfl_xor(s, 4);
                if (sl == 0) s_scores[x][j] = s;
            }
        }
    }
    __syncthreads();

    // ---- hat-basis AP epilogue: wave w owns match pos0+w (all 4 waves busy) ----
    const int w    = tid >> 6;
    const int lane = tid & 63;
    const int mpos = pos0 + w;
    if (mpos < N) {
        const float a_scale = qw[nq];               // +a
        const float amn     = qb[nq - 1] - 1.0f;    // a*mn
        const float ulim    = (float)(nq - 1);

        const float xp = s_scores[w][0];
        const float up = fminf(fmaxf(a_scale * xp - amn, 0.0f), ulim);
        const float ip = floorf(up);
        const float fp = up - ip;

        float n1 = 0.0f, n2 = 0.0f;
        {
            const float x  = s_scores[w][lane];
            const float u  = fminf(fmaxf(a_scale * x - amn, 0.0f), ulim);
            const float fi = floorf(u);
            const float f  = u - fi;
            n2 += (fi >= ip)        ? 1.0f : ((fi == ip - 1.0f) ? f : 0.0f);
            n1 += (fi >= ip + 1.0f) ? 1.0f : ((fi == ip)        ? f : 0.0f);
        }
        if (lane + 64 < M) {
            const float x  = s_scores[w][lane + 64];
            const float u  = fminf(fmaxf(a_scale * x - amn, 0.0f), ulim);
            const float fi = floorf(u);
            const float f  = u - fi;
            n2 += (fi >= ip)        ? 1.0f : ((fi == ip - 1.0f) ? f : 0.0f);
            n1 += (fi >= ip + 1.0f) ? 1.0f : ((fi == ip)        ? f : 0.0f);
        }
        #pragma unroll
        for (int off = 32; off >= 1; off >>= 1) {
            n1 += __shfl_xor(n1, off);
            n2 += __shfl_xor(n2, off);
        }
        if (lane == 0) {
            const float ap = fp * fp / (1e-16f + n1) + (1.0f - fp) / (1e-16f + n2);
            partial[mpos] = 1.0f - ap;
        }
    }
}

// ---- single-block final reduction (R0-proven) ----
__global__ __launch_bounds__(1024) void k_reduce(const float* __restrict__ partial,
                                                 float* __restrict__ out, int N)
{
    float s = 0.0f;
    for (int i = threadIdx.x; i < N; i += 1024) s += partial[i];
    #pragma unroll
    for (int off = 32; off >= 1; off >>= 1) s += __shfl_xor(s, off);
    __shared__ float sw[16];
    if ((threadIdx.x & 63) == 0) sw[threadIdx.x >> 6] = s;
    __syncthreads();
    if (threadIdx.x == 0) {
        float t = 0.0f;
        #pragma unroll
        for (int w = 0; w < 16; ++w) t += sw[w];
        out[0] = t / (float)N;
    }
}

// =====================================================================
extern "C" void kernel_launch(void* const* d_in, const int* in_sizes, int n_in,
                              void* d_out, int out_size, void* d_ws, size_t ws_size,
                              hipStream_t stream) {
    const float* d1   = (const float*)d_in[0];
    const float* d2   = (const float*)d_in[1];
    const float* qw   = (const float*)d_in[2];
    const float* qb   = (const float*)d_in[3];
    const int*   m1   = (const int*)d_in[4];
    const int*   m2   = (const int*)d_in[5];
    const int*   offs = (const int*)d_in[6];

    const int N     = in_sizes[4];
    const int P     = in_sizes[0] / DIM;
    const int NEG   = in_sizes[6];
    const int NQ2   = in_sizes[2];
    const int nbuck = (P + 127) >> 7;

    int*   cnt     = (int*)d_ws;
    int*   i1s     = cnt + nbuck;
    int*   i2s     = i1s + N;
    float* partial = (float*)(i2s + N);

    const int nblk = (N + 255) / 256;

    hipMemsetAsync(cnt, 0, (size_t)nbuck * sizeof(int), stream);
    k_hist   <<<nblk, 256, 0, stream>>>(m2, cnt, N);
    k_scan   <<<1, 256, 0, stream>>>(cnt, nbuck);
    k_scatter<<<nblk, 256, 0, stream>>>(m1, m2, cnt, i1s, i2s, N);

    const int nquad = (N + 3) / 4;
    const int per   = (nquad + 7) / 8;
    pixel_ap_main<<<8 * per, 256, 0, stream>>>(d1, d2, qw, qb, offs, i1s, i2s,
                                               partial, P, NEG, NQ2, N);

    k_reduce<<<1, 1024, 0, stream>>>(partial, (float*)d_out, N);
}

// Round 7
// 199.146 us; speedup vs baseline: 3.2295x; 1.0332x over previous
//
#include <hip/hip_runtime.h>

#define DIM 64

// ---- parallel counting-sort pipeline: zero(memset) -> hist -> scan -> scatter

__global__ __launch_bounds__(256) void k_hist(const int* __restrict__ m2,
                                              int* __restrict__ cnt, int N) {
    const int i = blockIdx.x * 256 + threadIdx.x;
    if (i < N) atomicAdd(&cnt[m2[i] >> 7], 1);
}

__global__ __launch_bounds__(256) void k_scan(int* __restrict__ cnt, int nbuck) {
    __shared__ int s[256];
    const int tid  = threadIdx.x;
    const int base = tid * 10;
    int loc[10];
    int sum = 0;
    #pragma unroll
    for (int u = 0; u < 10; ++u) {
        const int idx = base + u;
        const int v = (idx < nbuck) ? cnt[idx] : 0;
        loc[u] = sum;
        sum += v;
    }
    s[tid] = sum;
    __syncthreads();
    for (int off = 1; off < 256; off <<= 1) {
        const int v = (tid >= off) ? s[tid - off] : 0;
        __syncthreads();
        s[tid] += v;
        __syncthreads();
    }
    const int excl = (tid > 0) ? s[tid - 1] : 0;
    #pragma unroll
    for (int u = 0; u < 10; ++u) {
        const int idx = base + u;
        if (idx < nbuck) cnt[idx] = excl + loc[u];
    }
}

__global__ __launch_bounds__(256) void k_scatter(const int* __restrict__ m1,
                                                 const int* __restrict__ m2,
                                                 int* __restrict__ cnt,
                                                 int* __restrict__ i1s,
                                                 int* __restrict__ i2s, int N) {
    const int i = blockIdx.x * 256 + threadIdx.x;
    if (i < N) {
        const int v2  = m2[i];
        const int pos = atomicAdd(&cnt[v2 >> 7], 1);
        i1s[pos] = m1[i];
        i2s[pos] = v2;
    }
}

// ---- main: R0-proven shape (one block per TWO sorted matches), with ONE
//      change: sched_barrier(0) after the b-load loop. R0's VGPR=36 proves
//      the compiler was sinking the 12 loads into consumers (~6 in flight);
//      the fence forces all 12 issued before any math (true MLP). ----
__global__ __launch_bounds__(256) void pixel_ap_main(
    const float* __restrict__ d1, const float* __restrict__ d2,
    const float* __restrict__ qw, const float* __restrict__ qb,
    const int* __restrict__ offs,
    const int* __restrict__ i1s, const int* __restrict__ i2s,
    float* __restrict__ partial, int P, int NEG, int NQ2, int N)
{
    const int tid = threadIdx.x;
    const int nq  = NQ2 >> 1;
    const int M   = NEG + 1;          // 81 scores per match

    __shared__ float s_scores[2][96];

    // XCD-aware contiguous slice over pair-index space (block b -> XCD b%8)
    const int b    = blockIdx.x;
    const int per  = gridDim.x >> 3;                // gridDim = 8*per
    const int pr   = (b & 7) * per + (b >> 3);      // pair index
    const int posA = 2 * pr;
    const int posB = posA + 1;
    if (posA >= N) return;
    const bool hasB = (posB < N);

    const int i1A = i1s[posA];
    const int i2A = i2s[posA];
    const int i1B = hasB ? i1s[posB] : i1A;
    const int i2B = hasB ? i2s[posB] : i2A;

    const int g  = tid >> 3;          // group 0..31
    const int sl = tid & 7;           // 8 lanes x 32 B = 256 B per row

    // a fragments for both matches
    const float* aA = d1 + (size_t)i1A * DIM + 8 * sl;
    const float* aB = d1 + (size_t)i1B * DIM + 8 * sl;
    const float4 a0A = ((const float4*)aA)[0];
    const float4 a1A = ((const float4*)aA)[1];
    const float4 a0B = ((const float4*)aB)[0];
    const float4 a1B = ((const float4*)aB)[1];

    // row indices for 3 scores per match
    int rA[3], rB[3];
    #pragma unroll
    for (int t = 0; t < 3; ++t) {
        const int j = g + 32 * t;
        if (j < M) {
            const int o = (j == 0) ? 0 : offs[j - 1];
            rA[t] = (j == 0) ? i2A : min(i2A + o, P - 1);
            rB[t] = (j == 0) ? i2B : min(i2B + o, P - 1);
        }
    }

    // all 12 b-loads issued before any math
    float4 b0A[3], b1A[3], b0B[3], b1B[3];
    #pragma unroll
    for (int t = 0; t < 3; ++t) {
        const int j = g + 32 * t;
        if (j < M) {
            const float* pA = d2 + (size_t)rA[t] * DIM + 8 * sl;
            b0A[t] = ((const float4*)pA)[0];
            b1A[t] = ((const float4*)pA)[1];
            const float* pB = d2 + (size_t)rB[t] * DIM + 8 * sl;
            b0B[t] = ((const float4*)pB)[0];
            b1B[t] = ((const float4*)pB)[1];
        }
    }
    // Hard scheduling fence: nothing moves across. Forces the 12 loads
    // above to be issued before any dot-product math below.
    __builtin_amdgcn_sched_barrier(0);

    #pragma unroll
    for (int t = 0; t < 3; ++t) {
        const int j = g + 32 * t;
        if (j < M) {
            float sA = b0A[t].x * a0A.x + b0A[t].y * a0A.y + b0A[t].z * a0A.z + b0A[t].w * a0A.w
                     + b1A[t].x * a1A.x + b1A[t].y * a1A.y + b1A[t].z * a1A.z + b1A[t].w * a1A.w;
            float sB = b0B[t].x * a0B.x + b0B[t].y * a0B.y + b0B[t].z * a0B.z + b0B[t].w * a0B.w
                     + b1B[t].x * a1B.x + b1B[t].y * a1B.y + b1B[t].z * a1B.z + b1B[t].w * a1B.w;
            sA += __shfl_xor(sA, 1);
            sA += __shfl_xor(sA, 2);
            sA += __shfl_xor(sA, 4);
            sB += __shfl_xor(sB, 1);
            sB += __shfl_xor(sB, 2);
            sB += __shfl_xor(sB, 4);
            if (sl == 0) {
                s_scores[0][j] = sA;
                s_scores[1][j] = sB;
            }
        }
    }
    __syncthreads();
    const int w = tid >> 6;           // wave id
    if (w >= 2) return;               // waves 2,3 retire
    if (w == 1 && !hasB) return;
    const int lane = tid & 63;

    // ---- hat-basis AP epilogue, one wave per match ----
    const float a_scale = qw[nq];               // +a
    const float amn     = qb[nq - 1] - 1.0f;    // a*mn
    const float ulim    = (float)(nq - 1);

    const float xp = s_scores[w][0];
    const float up = fminf(fmaxf(a_scale * xp - amn, 0.0f), ulim);
    const float ip = floorf(up);
    const float fp = up - ip;

    float n1 = 0.0f, n2 = 0.0f;
    {
        const float x  = s_scores[w][lane];
        const float u  = fminf(fmaxf(a_scale * x - amn, 0.0f), ulim);
        const float fi = floorf(u);
        const float f  = u - fi;
        n2 += (fi >= ip)        ? 1.0f : ((fi == ip - 1.0f) ? f : 0.0f);
        n1 += (fi >= ip + 1.0f) ? 1.0f : ((fi == ip)        ? f : 0.0f);
    }
    if (lane + 64 < M) {
        const float x  = s_scores[w][lane + 64];
        const float u  = fminf(fmaxf(a_scale * x - amn, 0.0f), ulim);
        const float fi = floorf(u);
        const float f  = u - fi;
        n2 += (fi >= ip)        ? 1.0f : ((fi == ip - 1.0f) ? f : 0.0f);
        n1 += (fi >= ip + 1.0f) ? 1.0f : ((fi == ip)        ? f : 0.0f);
    }
    #pragma unroll
    for (int off = 32; off >= 1; off >>= 1) {
        n1 += __shfl_xor(n1, off);
        n2 += __shfl_xor(n2, off);
    }
    if (lane == 0) {
        const float ap = fp * fp / (1e-16f + n1) + (1.0f - fp) / (1e-16f + n2);
        partial[posA + w] = 1.0f - ap;
    }
}

// ---- single-block final reduction ----
__global__ __launch_bounds__(1024) void k_reduce(const float* __restrict__ partial,
                                                 float* __restrict__ out, int N)
{
    float s = 0.0f;
    for (int i = threadIdx.x; i < N; i += 1024) s += partial[i];
    #pragma unroll
    for (int off = 32; off >= 1; off >>= 1) s += __shfl_xor(s, off);
    __shared__ float sw[16];
    if ((threadIdx.x & 63) == 0) sw[threadIdx.x >> 6] = s;
    __syncthreads();
    if (threadIdx.x == 0) {
        float t = 0.0f;
        #pragma unroll
        for (int w = 0; w < 16; ++w) t += sw[w];
        out[0] = t / (float)N;
    }
}

extern "C" void kernel_launch(void* const* d_in, const int* in_sizes, int n_in,
                              void* d_out, int out_size, void* d_ws, size_t ws_size,
                              hipStream_t stream) {
    const float* d1   = (const float*)d_in[0];
    const float* d2   = (const float*)d_in[1];
    const float* qw   = (const float*)d_in[2];
    const float* qb   = (const float*)d_in[3];
    const int*   m1   = (const int*)d_in[4];
    const int*   m2   = (const int*)d_in[5];
    const int*   offs = (const int*)d_in[6];

    const int N     = in_sizes[4];
    const int P     = in_sizes[0] / DIM;
    const int NEG   = in_sizes[6];
    const int NQ2   = in_sizes[2];
    const int nbuck = (P + 127) >> 7;

    int*   cnt     = (int*)d_ws;
    int*   i1s     = cnt + nbuck;
    int*   i2s     = i1s + N;
    float* partial = (float*)(i2s + N);

    const int nblk = (N + 255) / 256;

    hipMemsetAsync(cnt, 0, (size_t)nbuck * sizeof(int), stream);
    k_hist   <<<nblk, 256, 0, stream>>>(m2, cnt, N);
    k_scan   <<<1, 256, 0, stream>>>(cnt, nbuck);
    k_scatter<<<nblk, 256, 0, stream>>>(m1, m2, cnt, i1s, i2s, N);

    const int npair = (N + 1) / 2;
    const int per   = (npair + 7) / 8;
    pixel_ap_main<<<8 * per, 256, 0, stream>>>(d1, d2, qw, qb, offs, i1s, i2s,
                                               partial, P, NEG, NQ2, N);

    k_reduce<<<1, 1024, 0, stream>>>(partial, (float*)d_out, N);
}